// Round 1
// 241.248 us; speedup vs baseline: 1.0424x; 1.0424x over previous
//
#include <hip/hip_runtime.h>
#include <hip/hip_bf16.h>
#include <math.h>

// Problem constants
#define BB 32
#define LL 4100
#define SS 1024
#define EE 16
#define HH 4
#define DHD 4
#define NCC 10

// Native exp2: single v_exp_f32; libm exp2f lowers to ~30-inst OCML (R6 finding).
#define EXP2(x) __builtin_amdgcn_exp2f(x)

typedef __attribute__((ext_vector_type(8))) short short8v;   // 8 bf16 = 4 VGPR (MFMA A/B)
typedef __attribute__((ext_vector_type(4))) float float4v;   // MFMA C/D

// Workspace layout (floats) — kept identical to previous round so the
// tsplit=4 workspace check and partO/partL placement are unchanged.
#define OFF_XSRC 0                        // B*S*16 = 524288
#define OFF_Q    524288                   // B*H*S*4 = 524288
#define OFF_K    1048576
#define OFF_V    1572864
#define OFF_H2   2377728                  // B*32*S = 1048576
#define OFF_PART 3950592                  // attn partials

// fp32 -> bf16 (RNE)
__device__ __forceinline__ short f2bf(float f) {
    union { float f; unsigned u; } a; a.f = f;
    unsigned r = (a.u + 0x7FFF + ((a.u >> 16) & 1)) >> 16;
    return (short)r;
}
// pack two fp32 -> bf16x2 (RNE)
__device__ __forceinline__ unsigned pk2bf(float a, float b) {
    union { __hip_bfloat162 h; unsigned u; } c;
    c.h = __float22bfloat162_rn(make_float2(a, b));
    return c.u;
}

// 16->16 projection to one of q/k/v: dst[(b*H+h)*S*4 + s*4 + d] = W[4h+d,:].t
__device__ __forceinline__ void proj16(const float* t, const float* __restrict__ W,
                                       float* __restrict__ dst, int b, int s) {
    #pragma unroll
    for (int h = 0; h < 4; h++) {
        float4 r;
        #pragma unroll
        for (int d = 0; d < 4; d++) {
            int e = h * 4 + d;
            float acc = 0.f;
            #pragma unroll
            for (int f = 0; f < 16; f++) acc += W[e * 16 + f] * t[f];
            ((float*)&r)[d] = acc;
        }
        ((float4*)(dst + ((size_t)(b * HH + h) * SS + s) * 4))[0] = r;
    }
}

// Inline PE (bit-identical to the old pe_kernel): pe[s][2j]=sin, pe[s][2j+1]=cos
__device__ __forceinline__ void pe_vals(int s, float* p) {
    #pragma unroll
    for (int j = 0; j < 8; j++) {
        float div = EXP2((float)j * -1.66096404744f);   // 10000^(-j/8)
        float ang = (float)s * div * (16.f / 1024.f);
        p[2 * j]     = __sinf(ang);
        p[2 * j + 1] = __cosf(ang);
    }
}

// Fused conv1 (1->8,k8,s4,valid,+BN+ReLU) + conv2 (8->32,k8,same,+BN+ReLU).
// Block = (s-tile of 256) x (o-group of 8) x b. h1 tile staged in LDS with
// halo [-3,+4]; invalid t stored as 0 == 'same' zero padding of conv2.
__global__ __launch_bounds__(256) void conv12(const float* __restrict__ x,
        const float* __restrict__ w1, const float* __restrict__ b1,
        const float* __restrict__ g1, const float* __restrict__ bb1,
        const float* __restrict__ w2, const float* __restrict__ b2,
        const float* __restrict__ g2, const float* __restrict__ bb2,
        float* __restrict__ h2) {
    __shared__ float h1t[8][264];       // t in [s0-3, s0+260]
    __shared__ float wsh[512];          // this o-group's conv2 weights
    int tid = threadIdx.x;
    int s0 = blockIdx.x * 256, ogrp = blockIdx.y, b = blockIdx.z;
    const float inv = rsqrtf(1.f + 1e-5f);
    for (int i = tid; i < 512; i += 256) wsh[i] = w2[ogrp * 512 + i];
    for (int i = tid; i < 8 * 264; i += 256) {
        int c = i / 264, j = i - c * 264;
        int tt = s0 - 3 + j;
        float vv = 0.f;
        if (tt >= 0 && tt < SS) {
            const float* xp = x + b * LL + 4 * tt;
            float a = b1[c];
            #pragma unroll
            for (int kk = 0; kk < 8; kk++) a += xp[kk] * w1[c * 8 + kk];
            vv = fmaxf(a * inv * g1[c] + bb1[c], 0.f);
        }
        h1t[c][j] = vv;
    }
    __syncthreads();
    float acc[8];
    #pragma unroll
    for (int o8 = 0; o8 < 8; o8++) acc[o8] = b2[ogrp * 8 + o8];
    #pragma unroll
    for (int i = 0; i < 8; i++) {
        float win[8];                    // 8-wide register window, reused by 8 o's
        #pragma unroll
        for (int kk = 0; kk < 8; kk++) win[kk] = h1t[i][tid + kk];
        #pragma unroll
        for (int o8 = 0; o8 < 8; o8++) {
            #pragma unroll
            for (int kk = 0; kk < 8; kk++)
                acc[o8] += win[kk] * wsh[(o8 * 8 + i) * 8 + kk];
        }
    }
    int s = s0 + tid;
    #pragma unroll
    for (int o8 = 0; o8 < 8; o8++) {
        int o = ogrp * 8 + o8;
        h2[((size_t)(b * 32 + o)) * SS + s] = fmaxf(acc[o8] * inv * g2[o] + bb2[o], 0.f);
    }
}

// Fused depthwise-grouped conv (32->16,k32,same,g16) + pointwise 16->16 +
// BN3 + ReLU + PE-add + layer-1 QKV projections (all 3 in one block).
// Block = (s-tile of 128) x b. h2 tile staged with halo [-15,+16].
__global__ __launch_bounds__(256) void dwpwqkv(const float* __restrict__ h2,
        const float* __restrict__ dwW, const float* __restrict__ pwm,
        const float* __restrict__ g3, const float* __restrict__ b3,
        const float* __restrict__ wq, const float* __restrict__ wk,
        const float* __restrict__ wv,
        float* __restrict__ xsrc, float* __restrict__ q,
        float* __restrict__ k, float* __restrict__ v) {
    __shared__ float h2t[32][161];      // t in [s0-15, s0+144)
    __shared__ float dwt[16][132];      // dw output tile [o][s-s0]
    __shared__ float dww[16 * 65];      // dw weights, stride 65 breaks bank alias
    int tid = threadIdx.x;
    int s0 = blockIdx.x * 128, b = blockIdx.y;
    for (int i = tid; i < 1024; i += 256) dww[(i >> 6) * 65 + (i & 63)] = dwW[i];
    for (int i = tid; i < 32 * 160; i += 256) {
        int c = i / 160, j = i - c * 160;
        int tt = s0 - 15 + j;
        h2t[c][j] = (tt >= 0 && tt < SS) ? h2[((size_t)(b * 32 + c)) * SS + tt] : 0.f;
    }
    __syncthreads();
    {   // dw: thread = (o, strip of 8 s); rotating 8-wide register window
        int o = tid >> 4, jb = (tid & 15) * 8;
        const float* r0 = &h2t[2 * o][jb];
        const float* r1 = &h2t[2 * o + 1][jb];
        const float* wp = &dww[o * 65];
        float win0[8], win1[8], acc[8];
        #pragma unroll
        for (int r = 0; r < 8; r++) { win0[r] = r0[r]; win1[r] = r1[r]; acc[r] = 0.f; }
        #pragma unroll
        for (int kk = 0; kk < 32; kk++) {
            float w0k = wp[kk], w1k = wp[32 + kk];
            #pragma unroll
            for (int r = 0; r < 8; r++)
                acc[r] += win0[(kk + r) & 7] * w0k + win1[(kk + r) & 7] * w1k;
            win0[kk & 7] = r0[kk + 8];     // slide window (max index 159, in-bounds)
            win1[kk & 7] = r1[kk + 8];
        }
        #pragma unroll
        for (int r = 0; r < 8; r += 4) {
            float4 f; f.x = acc[r]; f.y = acc[r + 1]; f.z = acc[r + 2]; f.w = acc[r + 3];
            *((float4*)&dwt[o][jb + r]) = f;
        }
    }
    __syncthreads();
    // pw + BN3 + ReLU + PE + QKV: 2 threads per s; half 0 -> Q,K; half 1 -> xsrc,V
    int sl = tid & 127, hv = tid >> 7;
    int s = s0 + sl;
    float gout[16];
    #pragma unroll
    for (int o = 0; o < 16; o++) gout[o] = dwt[o][sl];
    const float inv = rsqrtf(1.f + 1e-5f);
    float t[16];
    #pragma unroll
    for (int pq = 0; pq < 16; pq++) {
        float a = 0.f;
        #pragma unroll
        for (int o = 0; o < 16; o++) a += pwm[pq * 16 + o] * gout[o];
        t[pq] = fmaxf(a * inv * g3[pq] + b3[pq], 0.f);
    }
    if (hv) {
        float4* xp = (float4*)(xsrc + ((size_t)(b * SS + s)) * 16);
        #pragma unroll
        for (int i = 0; i < 4; i++) {
            float4 f; f.x = t[4*i]; f.y = t[4*i+1]; f.z = t[4*i+2]; f.w = t[4*i+3];
            xp[i] = f;
        }
    }
    float pef[16]; pe_vals(s, pef);
    #pragma unroll
    for (int e = 0; e < 16; e++) t[e] += pef[e];
    if (!hv) { proj16(t, wq, q, b, s); proj16(t, wk, k, b, s); }
    else     { proj16(t, wv, v, b, s); }
}

// MFMA flash attention with chunk prefetch (unchanged structure; Vtsh rows
// 5..15 no longer zeroed — MFMA D rows are independent and rows 5..15 of the
// output are never read, so garbage there is harmless).
template <int TC>
__global__ __launch_bounds__(256) void attn_mfma(const float* __restrict__ q,
        const float* __restrict__ k, const float* __restrict__ v,
        float* __restrict__ partO, float* __restrict__ partL) {
    constexpr int NCH = TC / 32;
    __shared__ __align__(16) short Ksh[TC * 4];          // [t][d] bf16
    __shared__ __align__(16) short Vtsh[16][TC + 8];     // [n][t] bf16
    __shared__ __align__(16) unsigned Psh[4][16 * 20];   // per-wave P tile
    int bh = blockIdx.x, sblk = blockIdx.y, tc = blockIdx.z;
    int tid = threadIdx.x;
    int wave = tid >> 6, lane = tid & 63;
    int col = lane & 15, quad = lane >> 4;
    int t0 = tc * TC;

    const float4* kg = (const float4*)(k + (size_t)bh * SS * 4) + t0;
    const float4* vg = (const float4*)(v + (size_t)bh * SS * 4) + t0;
    for (int t = tid; t < TC; t += 256) {
        float4 kk = kg[t];
        Ksh[t * 4 + 0] = f2bf(kk.x); Ksh[t * 4 + 1] = f2bf(kk.y);
        Ksh[t * 4 + 2] = f2bf(kk.z); Ksh[t * 4 + 3] = f2bf(kk.w);
        float4 vv = vg[t];
        Vtsh[0][t] = f2bf(vv.x); Vtsh[1][t] = f2bf(vv.y);
        Vtsh[2][t] = f2bf(vv.z); Vtsh[3][t] = f2bf(vv.w);
        Vtsh[4][t] = (short)0x3F80;                      // ones row -> l = sum(p)
    }
    __syncthreads();

    int s0 = sblk * 64 + wave * 16;
    int sg = s0 + col;
    short8v bq = {0, 0, 0, 0, 0, 0, 0, 0};
    {
        const float cfold = 1.44269504089f / 4096.f;     // log2(e) * scale/n
        float4 qq = ((const float4*)(q + (size_t)bh * SS * 4))[sg];
        if (quad == 0) {
            bq[0] = f2bf(qq.x * cfold); bq[1] = f2bf(qq.y * cfold);
            bq[2] = f2bf(qq.z * cfold); bq[3] = f2bf(qq.w * cfold);
        }
    }
    float tf[8];
    #pragma unroll
    for (int r = 0; r < 8; r++)
        tf[r] = (float)(t0 + (r >> 2) * 16 + quad * 4 + (r & 3) - sg);
    float4v acc = {0.f, 0.f, 0.f, 0.f};
    unsigned* Pw = Psh[wave];
    // prefetch chunk 0 operands
    short8v a0 = {0,0,0,0,0,0,0,0}, a1 = {0,0,0,0,0,0,0,0};
    if (quad == 0) {
        int tb = col * 4;
        a0[0]=Ksh[tb+0]; a0[1]=Ksh[tb+1]; a0[2]=Ksh[tb+2]; a0[3]=Ksh[tb+3];
        a1[0]=Ksh[tb+64]; a1[1]=Ksh[tb+65]; a1[2]=Ksh[tb+66]; a1[3]=Ksh[tb+67];
    }
    short8v av = *((const short8v*)&Vtsh[col][quad * 8]);
    for (int ch = 0; ch < NCH; ch++) {
        float4v z = {0.f, 0.f, 0.f, 0.f};
        float4v c0 = __builtin_amdgcn_mfma_f32_16x16x32_bf16(a0, bq, z, 0, 0, 0);
        float4v c1 = __builtin_amdgcn_mfma_f32_16x16x32_bf16(a1, bq, z, 0, 0, 0);
        // prefetch next chunk while MFMA results land
        short8v a0n = {0,0,0,0,0,0,0,0}, a1n = {0,0,0,0,0,0,0,0}, avn = {0,0,0,0,0,0,0,0};
        if (ch + 1 < NCH) {
            if (quad == 0) {
                int tb = ((ch + 1) * 32 + col) * 4;
                a0n[0]=Ksh[tb+0]; a0n[1]=Ksh[tb+1]; a0n[2]=Ksh[tb+2]; a0n[3]=Ksh[tb+3];
                a1n[0]=Ksh[tb+64]; a1n[1]=Ksh[tb+65]; a1n[2]=Ksh[tb+66]; a1n[3]=Ksh[tb+67];
            }
            avn = *((const short8v*)&Vtsh[col][(ch + 1) * 32 + quad * 8]);
        }
        float p[8];
        #pragma unroll
        for (int r = 0; r < 4; r++) {
            p[r]     = EXP2(c0[r] * fabsf(tf[r]));     tf[r] += 32.f;
            p[4 + r] = EXP2(c1[r] * fabsf(tf[4 + r])); tf[4 + r] += 32.f;
        }
        unsigned base = col * 20 + quad * 2;
        Pw[base + 0] = pk2bf(p[0], p[1]);
        Pw[base + 1] = pk2bf(p[2], p[3]);
        Pw[base + 8] = pk2bf(p[4], p[5]);
        Pw[base + 9] = pk2bf(p[6], p[7]);
        short8v pb = *((const short8v*)&Pw[col * 20 + quad * 4]);
        acc = __builtin_amdgcn_mfma_f32_16x16x32_bf16(av, pb, acc, 0, 0, 0);
        a0 = a0n; a1 = a1n; av = avn;
    }
    size_t o = (size_t)(tc * (BB * HH) + bh) * SS + sg;
    if (quad == 0) {
        float4 r; r.x = acc[0]; r.y = acc[1]; r.z = acc[2]; r.w = acc[3];
        ((float4*)partO)[o] = r;
    } else if (quad == 1) {
        partL[o] = acc[0];                                // ones column = sum(p)
    }
}

// Layer-1 epilogue fused with ALL layer-2 QKV projections (3-way split merged
// => partial-reduce + double-LN done once instead of 3x) + inline PE.
__global__ __launch_bounds__(128) void post_qkv2(const float* __restrict__ partO,
        const float* __restrict__ partL, int nsplit,
        const float* __restrict__ res,
        const float* __restrict__ lnag, const float* __restrict__ lnab,
        const float* __restrict__ lng, const float* __restrict__ lnb,
        const float* __restrict__ wq, const float* __restrict__ wk,
        const float* __restrict__ wv,
        float* __restrict__ q, float* __restrict__ k, float* __restrict__ v) {
    int idx = blockIdx.x * 128 + threadIdx.x;       // b*S + s
    int s = idx & 1023, b = idx >> 10;
    float t[16];
    #pragma unroll
    for (int h = 0; h < HH; h++) {
        int bh = b * HH + h;
        float ox = 0.f, oy = 0.f, oz = 0.f, ow = 0.f, l = 0.f;
        for (int c = 0; c < nsplit; c++) {
            size_t o = (size_t)(c * (BB * HH) + bh) * SS + s;
            float4 O = ((const float4*)partO)[o];
            ox += O.x; oy += O.y; oz += O.z; ow += O.w;
            l += partL[o];
        }
        float rl = 1.f / l;
        t[h*4+0] = ox * rl; t[h*4+1] = oy * rl;
        t[h*4+2] = oz * rl; t[h*4+3] = ow * rl;
    }
    float mu = 0.f;
    #pragma unroll
    for (int e = 0; e < 16; e++) mu += t[e];
    mu *= (1.f / 16.f);
    float var = 0.f;
    #pragma unroll
    for (int e = 0; e < 16; e++) { float d = t[e] - mu; var += d * d; }
    var *= (1.f / 16.f);
    float r = rsqrtf(var + 1e-5f);
    const float4* rp = (const float4*)(res + ((size_t)b * SS + s) * 16);
    #pragma unroll
    for (int i = 0; i < 4; i++) {
        float4 a = rp[i];
        t[4*i+0] = (t[4*i+0]-mu)*r*lnag[4*i+0] + lnab[4*i+0] + a.x;
        t[4*i+1] = (t[4*i+1]-mu)*r*lnag[4*i+1] + lnab[4*i+1] + a.y;
        t[4*i+2] = (t[4*i+2]-mu)*r*lnag[4*i+2] + lnab[4*i+2] + a.z;
        t[4*i+3] = (t[4*i+3]-mu)*r*lnag[4*i+3] + lnab[4*i+3] + a.w;
    }
    float mu2 = 0.f;
    #pragma unroll
    for (int e = 0; e < 16; e++) mu2 += t[e];
    mu2 *= (1.f / 16.f);
    float var2 = 0.f;
    #pragma unroll
    for (int e = 0; e < 16; e++) { float d = t[e] - mu2; var2 += d * d; }
    var2 *= (1.f / 16.f);
    float r2 = rsqrtf(var2 + 1e-5f);
    float pef[16]; pe_vals(s, pef);
    #pragma unroll
    for (int e = 0; e < 16; e++)
        t[e] = (t[e]-mu2)*r2*lng[e] + lnb[e] + pef[e];
    proj16(t, wq, q, b, s);
    proj16(t, wk, k, b, s);
    proj16(t, wv, v, b, s);
}

// Layer-2 epilogue + global average pool over full S + 16->10 linear, one
// block per b (1024 threads = 1024 s), shuffle-tree reduction.
__global__ __launch_bounds__(1024) void postpool(const float* __restrict__ partO,
        const float* __restrict__ partL, int nsplit,
        const float* __restrict__ lnag, const float* __restrict__ lnab,
        const float* __restrict__ lng, const float* __restrict__ lnb,
        const float* __restrict__ ow, const float* __restrict__ ob,
        float* __restrict__ out) {
    __shared__ float red[16 * 17];
    __shared__ float pooled[16];
    int tid = threadIdx.x;
    int s = tid, b = blockIdx.x;
    float t[16];
    #pragma unroll
    for (int h = 0; h < HH; h++) {
        int bh = b * HH + h;
        float ox = 0.f, oy = 0.f, oz = 0.f, owv = 0.f, l = 0.f;
        for (int c = 0; c < nsplit; c++) {
            size_t o = (size_t)(c * (BB * HH) + bh) * SS + s;
            float4 O = ((const float4*)partO)[o];
            ox += O.x; oy += O.y; oz += O.z; owv += O.w;
            l += partL[o];
        }
        float rl = 1.f / l;
        t[h*4+0] = ox * rl; t[h*4+1] = oy * rl;
        t[h*4+2] = oz * rl; t[h*4+3] = owv * rl;
    }
    float mu = 0.f;
    #pragma unroll
    for (int e = 0; e < 16; e++) mu += t[e];
    mu *= (1.f / 16.f);
    float var = 0.f;
    #pragma unroll
    for (int e = 0; e < 16; e++) { float d = t[e] - mu; var += d * d; }
    var *= (1.f / 16.f);
    float r = rsqrtf(var + 1e-5f);
    #pragma unroll
    for (int e = 0; e < 16; e++) t[e] = (t[e]-mu)*r*lnag[e] + lnab[e];
    float mu2 = 0.f;
    #pragma unroll
    for (int e = 0; e < 16; e++) mu2 += t[e];
    mu2 *= (1.f / 16.f);
    float var2 = 0.f;
    #pragma unroll
    for (int e = 0; e < 16; e++) { float d = t[e] - mu2; var2 += d * d; }
    var2 *= (1.f / 16.f);
    float r2 = rsqrtf(var2 + 1e-5f);
    #pragma unroll
    for (int e = 0; e < 16; e++) t[e] = (t[e]-mu2)*r2*lng[e] + lnb[e];
    // per-wave shuffle reduction over 64 s-positions
    #pragma unroll
    for (int e = 0; e < 16; e++) {
        float vsum = t[e];
        vsum += __shfl_down(vsum, 32);
        vsum += __shfl_down(vsum, 16);
        vsum += __shfl_down(vsum, 8);
        vsum += __shfl_down(vsum, 4);
        vsum += __shfl_down(vsum, 2);
        vsum += __shfl_down(vsum, 1);
        t[e] = vsum;
    }
    if ((tid & 63) == 0) {
        int wv = tid >> 6;
        #pragma unroll
        for (int e = 0; e < 16; e++) red[wv * 17 + e] = t[e];
    }
    __syncthreads();
    if (tid < 16) {
        float a = 0.f;
        #pragma unroll
        for (int wv = 0; wv < 16; wv++) a += red[wv * 17 + tid];
        pooled[tid] = a;
    }
    __syncthreads();
    if (tid < NCC) {
        float a = ob[tid];
        #pragma unroll
        for (int e = 0; e < 16; e++) a += pooled[e] * (1.f / 1024.f) * ow[tid * 16 + e];
        out[b * NCC + tid] = a;
    }
}

extern "C" void kernel_launch(void* const* d_in, const int* in_sizes, int n_in,
                              void* d_out, int out_size, void* d_ws, size_t ws_size,
                              hipStream_t stream) {
    const float* x       = (const float*)d_in[0];
    const float* patch_w = (const float*)d_in[1];
    const float* patch_b = (const float*)d_in[2];
    const float* bn1_g   = (const float*)d_in[3];
    const float* bn1_b   = (const float*)d_in[4];
    const float* emb_w   = (const float*)d_in[5];
    const float* emb_b   = (const float*)d_in[6];
    const float* bn2_g   = (const float*)d_in[7];
    const float* bn2_b   = (const float*)d_in[8];
    const float* dw_w    = (const float*)d_in[9];
    const float* pw_w    = (const float*)d_in[10];
    const float* bn3_g   = (const float*)d_in[11];
    const float* bn3_b   = (const float*)d_in[12];
    const float* q1_w    = (const float*)d_in[13];
    const float* k1_w    = (const float*)d_in[14];
    const float* v1_w    = (const float*)d_in[15];
    const float* lna1_g  = (const float*)d_in[16];
    const float* lna1_b  = (const float*)d_in[17];
    const float* ln1_g   = (const float*)d_in[18];
    const float* ln1_b   = (const float*)d_in[19];
    const float* q2_w    = (const float*)d_in[20];
    const float* k2_w    = (const float*)d_in[21];
    const float* v2_w    = (const float*)d_in[22];
    const float* lna2_g  = (const float*)d_in[23];
    const float* lna2_b  = (const float*)d_in[24];
    const float* ln2_g   = (const float*)d_in[25];
    const float* ln2_b   = (const float*)d_in[26];
    const float* out_w   = (const float*)d_in[27];
    const float* out_b   = (const float*)d_in[28];

    float* ws    = (float*)d_ws;
    float* xsrc  = ws + OFF_XSRC;
    float* q     = ws + OFF_Q;
    float* k     = ws + OFF_K;
    float* v     = ws + OFF_V;
    float* h2    = ws + OFF_H2;
    float* out   = (float*)d_out;

    // attn t-split: 4-way (TC=256) if workspace allows, else 2-way (TC=512)
    int tsplit; float *partO, *partL;
    size_t need4 = (size_t)(OFF_PART + 4 * 131072 * 5) * 4;
    if (ws_size >= need4) {
        tsplit = 4;
        partO = ws + OFF_PART;
        partL = ws + OFF_PART + 4 * 131072 * 4;
    } else {
        tsplit = 2;
        partO = ws + OFF_PART;
        partL = ws + OFF_PART + 2 * 131072 * 4;
    }

    conv12<<<dim3(4, 4, BB), 256, 0, stream>>>(x, patch_w, patch_b, bn1_g, bn1_b,
        emb_w, emb_b, bn2_g, bn2_b, h2);
    dwpwqkv<<<dim3(8, BB), 256, 0, stream>>>(h2, dw_w, pw_w, bn3_g, bn3_b,
        q1_w, k1_w, v1_w, xsrc, q, k, v);

    dim3 agrid(BB * HH, 16, tsplit);
    if (tsplit == 4) attn_mfma<256><<<agrid, 256, 0, stream>>>(q, k, v, partO, partL);
    else             attn_mfma<512><<<agrid, 256, 0, stream>>>(q, k, v, partO, partL);

    post_qkv2<<<dim3(256), 128, 0, stream>>>(partO, partL, tsplit, xsrc,
        lna1_g, lna1_b, ln1_g, ln1_b, q2_w, k2_w, v2_w, q, k, v);

    if (tsplit == 4) attn_mfma<256><<<agrid, 256, 0, stream>>>(q, k, v, partO, partL);
    else             attn_mfma<512><<<agrid, 256, 0, stream>>>(q, k, v, partO, partL);

    postpool<<<dim3(BB), 1024, 0, stream>>>(partO, partL, tsplit,
        lna2_g, lna2_b, ln2_g, ln2_b, out_w, out_b, out);
}

// Round 2
// 241.175 us; speedup vs baseline: 1.0427x; 1.0003x over previous
//
#include <hip/hip_runtime.h>
#include <hip/hip_bf16.h>
#include <math.h>

// Problem constants
#define BB 32
#define LL 4100
#define SS 1024
#define EE 16
#define HH 4
#define DHD 4
#define NCC 10

// Native exp2: single v_exp_f32; libm exp2f lowers to ~30-inst OCML (R6 finding).
#define EXP2(x) __builtin_amdgcn_exp2f(x)

typedef __attribute__((ext_vector_type(8))) short short8v;   // 8 bf16 = 4 VGPR (MFMA A/B)
typedef __attribute__((ext_vector_type(4))) float float4v;   // MFMA C/D

// Workspace layout (floats)
#define OFF_XSRC 0                        // B*S*16 = 524288
#define OFF_Q    524288                   // B*H*S*4 = 524288
#define OFF_K    1048576
#define OFF_V    1572864
#define OFF_H2   2377728                  // B*32*S = 1048576
#define OFF_PART 3950592                  // attn partials; poolp follows

// fp32 -> bf16 (RNE)
__device__ __forceinline__ short f2bf(float f) {
    union { float f; unsigned u; } a; a.f = f;
    unsigned r = (a.u + 0x7FFF + ((a.u >> 16) & 1)) >> 16;
    return (short)r;
}
// pack two fp32 -> bf16x2 (RNE)
__device__ __forceinline__ unsigned pk2bf(float a, float b) {
    union { __hip_bfloat162 h; unsigned u; } c;
    c.h = __float22bfloat162_rn(make_float2(a, b));
    return c.u;
}

// 16->16 projection to one of q/k/v: dst[(b*H+h)*S*4 + s*4 + d] = W[4h+d,:].t
__device__ __forceinline__ void proj16(const float* t, const float* __restrict__ W,
                                       float* __restrict__ dst, int b, int s) {
    #pragma unroll
    for (int h = 0; h < 4; h++) {
        float4 r;
        #pragma unroll
        for (int d = 0; d < 4; d++) {
            int e = h * 4 + d;
            float acc = 0.f;
            #pragma unroll
            for (int f = 0; f < 16; f++) acc += W[e * 16 + f] * t[f];
            ((float*)&r)[d] = acc;
        }
        ((float4*)(dst + ((size_t)(b * HH + h) * SS + s) * 4))[0] = r;
    }
}

// Inline PE (bit-identical to the old pe_kernel): pe[s][2j]=sin, pe[s][2j+1]=cos
__device__ __forceinline__ void pe_vals(int s, float* p) {
    #pragma unroll
    for (int j = 0; j < 8; j++) {
        float div = EXP2((float)j * -1.66096404744f);   // 10000^(-j/8)
        float ang = (float)s * div * (16.f / 1024.f);
        p[2 * j]     = __sinf(ang);
        p[2 * j + 1] = __cosf(ang);
    }
}

// Fused conv1 (1->8,k8,s4,valid,+BN+ReLU) + conv2 (8->32,k8,same,+BN+ReLU).
// conv2 weights read via thread-uniform global indices -> scalar loads, no LDS.
__global__ __launch_bounds__(256) void conv12(const float* __restrict__ x,
        const float* __restrict__ w1, const float* __restrict__ b1,
        const float* __restrict__ g1, const float* __restrict__ bb1,
        const float* __restrict__ w2, const float* __restrict__ b2,
        const float* __restrict__ g2, const float* __restrict__ bb2,
        float* __restrict__ h2) {
    __shared__ float h1t[8][264];       // t in [s0-3, s0+260]
    int tid = threadIdx.x;
    int s0 = blockIdx.x * 256, ogrp = blockIdx.y, b = blockIdx.z;
    const float inv = rsqrtf(1.f + 1e-5f);
    for (int i = tid; i < 8 * 264; i += 256) {
        int c = i / 264, j = i - c * 264;
        int tt = s0 - 3 + j;
        float vv = 0.f;
        if (tt >= 0 && tt < SS) {
            const float* xp = x + b * LL + 4 * tt;
            float a = b1[c];
            #pragma unroll
            for (int kk = 0; kk < 8; kk++) a += xp[kk] * w1[c * 8 + kk];
            vv = fmaxf(a * inv * g1[c] + bb1[c], 0.f);
        }
        h1t[c][j] = vv;
    }
    __syncthreads();
    float acc[8];
    #pragma unroll
    for (int o8 = 0; o8 < 8; o8++) acc[o8] = b2[ogrp * 8 + o8];
    #pragma unroll
    for (int i = 0; i < 8; i++) {
        float win[8];                    // 8-wide register window, reused by 8 o's
        #pragma unroll
        for (int kk = 0; kk < 8; kk++) win[kk] = h1t[i][tid + kk];
        #pragma unroll
        for (int o8 = 0; o8 < 8; o8++) {
            #pragma unroll
            for (int kk = 0; kk < 8; kk++)
                acc[o8] += win[kk] * w2[((ogrp * 8 + o8) * 8 + i) * 8 + kk];
        }
    }
    int s = s0 + tid;
    #pragma unroll
    for (int o8 = 0; o8 < 8; o8++) {
        int o = ogrp * 8 + o8;
        h2[((size_t)(b * 32 + o)) * SS + s] = fmaxf(acc[o8] * inv * g2[o] + bb2[o], 0.f);
    }
}

// Fused depthwise-grouped conv (32->16,k32,same,g16) + pointwise 16->16 +
// BN3 + ReLU + PE-add + layer-1 QKV projections.
__global__ __launch_bounds__(256) void dwpwqkv(const float* __restrict__ h2,
        const float* __restrict__ dwW, const float* __restrict__ pwm,
        const float* __restrict__ g3, const float* __restrict__ b3,
        const float* __restrict__ wq, const float* __restrict__ wk,
        const float* __restrict__ wv,
        float* __restrict__ xsrc, float* __restrict__ q,
        float* __restrict__ k, float* __restrict__ v) {
    __shared__ float h2t[32][161];      // t in [s0-15, s0+144)
    __shared__ float dwt[16][132];      // dw output tile [o][s-s0]
    __shared__ float dww[16 * 65];      // dw weights, stride 65 breaks bank alias
    int tid = threadIdx.x;
    int s0 = blockIdx.x * 128, b = blockIdx.y;
    for (int i = tid; i < 1024; i += 256) dww[(i >> 6) * 65 + (i & 63)] = dwW[i];
    for (int i = tid; i < 32 * 160; i += 256) {
        int c = i / 160, j = i - c * 160;
        int tt = s0 - 15 + j;
        h2t[c][j] = (tt >= 0 && tt < SS) ? h2[((size_t)(b * 32 + c)) * SS + tt] : 0.f;
    }
    __syncthreads();
    {   // dw: thread = (o, strip of 8 s); rotating 8-wide register window
        int o = tid >> 4, jb = (tid & 15) * 8;
        const float* r0 = &h2t[2 * o][jb];
        const float* r1 = &h2t[2 * o + 1][jb];
        const float* wp = &dww[o * 65];
        float win0[8], win1[8], acc[8];
        #pragma unroll
        for (int r = 0; r < 8; r++) { win0[r] = r0[r]; win1[r] = r1[r]; acc[r] = 0.f; }
        #pragma unroll
        for (int kk = 0; kk < 32; kk++) {
            float w0k = wp[kk], w1k = wp[32 + kk];
            #pragma unroll
            for (int r = 0; r < 8; r++)
                acc[r] += win0[(kk + r) & 7] * w0k + win1[(kk + r) & 7] * w1k;
            win0[kk & 7] = r0[kk + 8];     // slide window (max index 159, in-bounds)
            win1[kk & 7] = r1[kk + 8];
        }
        #pragma unroll
        for (int r = 0; r < 8; r += 4) {
            float4 f; f.x = acc[r]; f.y = acc[r + 1]; f.z = acc[r + 2]; f.w = acc[r + 3];
            *((float4*)&dwt[o][jb + r]) = f;
        }
    }
    __syncthreads();
    // pw + BN3 + ReLU + PE + QKV: 2 threads per s; half 0 -> Q,K; half 1 -> xsrc,V
    int sl = tid & 127, hv = tid >> 7;
    int s = s0 + sl;
    float gout[16];
    #pragma unroll
    for (int o = 0; o < 16; o++) gout[o] = dwt[o][sl];
    const float inv = rsqrtf(1.f + 1e-5f);
    float t[16];
    #pragma unroll
    for (int pq = 0; pq < 16; pq++) {
        float a = 0.f;
        #pragma unroll
        for (int o = 0; o < 16; o++) a += pwm[pq * 16 + o] * gout[o];
        t[pq] = fmaxf(a * inv * g3[pq] + b3[pq], 0.f);
    }
    if (hv) {
        float4* xp = (float4*)(xsrc + ((size_t)(b * SS + s)) * 16);
        #pragma unroll
        for (int i = 0; i < 4; i++) {
            float4 f; f.x = t[4*i]; f.y = t[4*i+1]; f.z = t[4*i+2]; f.w = t[4*i+3];
            xp[i] = f;
        }
    }
    float pef[16]; pe_vals(s, pef);
    #pragma unroll
    for (int e = 0; e < 16; e++) t[e] += pef[e];
    if (!hv) { proj16(t, wq, q, b, s); proj16(t, wk, k, b, s); }
    else     { proj16(t, wv, v, b, s); }
}

// MFMA flash attention with chunk prefetch.
template <int TC>
__global__ __launch_bounds__(256) void attn_mfma(const float* __restrict__ q,
        const float* __restrict__ k, const float* __restrict__ v,
        float* __restrict__ partO, float* __restrict__ partL) {
    constexpr int NCH = TC / 32;
    __shared__ __align__(16) short Ksh[TC * 4];          // [t][d] bf16
    __shared__ __align__(16) short Vtsh[16][TC + 8];     // [n][t] bf16
    __shared__ __align__(16) unsigned Psh[4][16 * 20];   // per-wave P tile
    int bh = blockIdx.x, sblk = blockIdx.y, tc = blockIdx.z;
    int tid = threadIdx.x;
    int wave = tid >> 6, lane = tid & 63;
    int col = lane & 15, quad = lane >> 4;
    int t0 = tc * TC;

    const float4* kg = (const float4*)(k + (size_t)bh * SS * 4) + t0;
    const float4* vg = (const float4*)(v + (size_t)bh * SS * 4) + t0;
    for (int t = tid; t < TC; t += 256) {
        float4 kk = kg[t];
        uint2 kw; kw.x = pk2bf(kk.x, kk.y); kw.y = pk2bf(kk.z, kk.w);
        *((uint2*)&Ksh[t * 4]) = kw;                     // one ds_write_b64
        float4 vv = vg[t];
        Vtsh[0][t] = f2bf(vv.x); Vtsh[1][t] = f2bf(vv.y);
        Vtsh[2][t] = f2bf(vv.z); Vtsh[3][t] = f2bf(vv.w);
        Vtsh[4][t] = (short)0x3F80;                      // ones row -> l = sum(p)
    }
    __syncthreads();

    int s0 = sblk * 64 + wave * 16;
    int sg = s0 + col;
    short8v bq = {0, 0, 0, 0, 0, 0, 0, 0};
    {
        const float cfold = 1.44269504089f / 4096.f;     // log2(e) * scale/n
        float4 qq = ((const float4*)(q + (size_t)bh * SS * 4))[sg];
        if (quad == 0) {
            bq[0] = f2bf(qq.x * cfold); bq[1] = f2bf(qq.y * cfold);
            bq[2] = f2bf(qq.z * cfold); bq[3] = f2bf(qq.w * cfold);
        }
    }
    float tf[8];
    #pragma unroll
    for (int r = 0; r < 8; r++)
        tf[r] = (float)(t0 + (r >> 2) * 16 + quad * 4 + (r & 3) - sg);
    float4v acc = {0.f, 0.f, 0.f, 0.f};
    unsigned* Pw = Psh[wave];
    // prefetch chunk 0 operands
    short8v a0 = {0,0,0,0,0,0,0,0}, a1 = {0,0,0,0,0,0,0,0};
    if (quad == 0) {
        int tb = col * 4;
        a0[0]=Ksh[tb+0]; a0[1]=Ksh[tb+1]; a0[2]=Ksh[tb+2]; a0[3]=Ksh[tb+3];
        a1[0]=Ksh[tb+64]; a1[1]=Ksh[tb+65]; a1[2]=Ksh[tb+66]; a1[3]=Ksh[tb+67];
    }
    short8v av = *((const short8v*)&Vtsh[col][quad * 8]);
    for (int ch = 0; ch < NCH; ch++) {
        float4v z = {0.f, 0.f, 0.f, 0.f};
        float4v c0 = __builtin_amdgcn_mfma_f32_16x16x32_bf16(a0, bq, z, 0, 0, 0);
        float4v c1 = __builtin_amdgcn_mfma_f32_16x16x32_bf16(a1, bq, z, 0, 0, 0);
        // prefetch next chunk while MFMA results land
        short8v a0n = {0,0,0,0,0,0,0,0}, a1n = {0,0,0,0,0,0,0,0}, avn = {0,0,0,0,0,0,0,0};
        if (ch + 1 < NCH) {
            if (quad == 0) {
                int tb = ((ch + 1) * 32 + col) * 4;
                a0n[0]=Ksh[tb+0]; a0n[1]=Ksh[tb+1]; a0n[2]=Ksh[tb+2]; a0n[3]=Ksh[tb+3];
                a1n[0]=Ksh[tb+64]; a1n[1]=Ksh[tb+65]; a1n[2]=Ksh[tb+66]; a1n[3]=Ksh[tb+67];
            }
            avn = *((const short8v*)&Vtsh[col][(ch + 1) * 32 + quad * 8]);
        }
        float p[8];
        #pragma unroll
        for (int r = 0; r < 4; r++) {
            p[r]     = EXP2(c0[r] * fabsf(tf[r]));     tf[r] += 32.f;
            p[4 + r] = EXP2(c1[r] * fabsf(tf[4 + r])); tf[4 + r] += 32.f;
        }
        unsigned base = col * 20 + quad * 2;
        Pw[base + 0] = pk2bf(p[0], p[1]);
        Pw[base + 1] = pk2bf(p[2], p[3]);
        Pw[base + 8] = pk2bf(p[4], p[5]);
        Pw[base + 9] = pk2bf(p[6], p[7]);
        short8v pb = *((const short8v*)&Pw[col * 20 + quad * 4]);
        acc = __builtin_amdgcn_mfma_f32_16x16x32_bf16(av, pb, acc, 0, 0, 0);
        a0 = a0n; a1 = a1n; av = avn;
    }
    size_t o = (size_t)(tc * (BB * HH) + bh) * SS + sg;
    if (quad == 0) {
        float4 r; r.x = acc[0]; r.y = acc[1]; r.z = acc[2]; r.w = acc[3];
        ((float4*)partO)[o] = r;
    } else if (quad == 1) {
        partL[o] = acc[0];                                // ones column = sum(p)
    }
}

// Layer-1 epilogue fused with layer-2 QKV. 256 threads: pairs of threads split
// the 4-head partial-reduce (2 heads each, exchanged via LDS); grp0 projects
// Q+K, grp1 projects V. Double the waves, half the partO loads per thread.
__global__ __launch_bounds__(256) void post_qkv2(const float* __restrict__ partO,
        const float* __restrict__ partL, int nsplit,
        const float* __restrict__ res,
        const float* __restrict__ lnag, const float* __restrict__ lnab,
        const float* __restrict__ lng, const float* __restrict__ lnb,
        const float* __restrict__ wq, const float* __restrict__ wk,
        const float* __restrict__ wv,
        float* __restrict__ q, float* __restrict__ k, float* __restrict__ v) {
    __shared__ float xch[2][128][9];
    int tid = threadIdx.x;
    int sl = tid & 127, grp = tid >> 7;
    int idx = blockIdx.x * 128 + sl;               // b*S + s
    int s = idx & 1023, b = idx >> 10;
    float t[16];
    #pragma unroll
    for (int hh = 0; hh < 2; hh++) {
        int h = grp * 2 + hh;
        int bh = b * HH + h;
        float ox = 0.f, oy = 0.f, oz = 0.f, ow = 0.f, l = 0.f;
        for (int c = 0; c < nsplit; c++) {
            size_t o = (size_t)(c * (BB * HH) + bh) * SS + s;
            float4 O = ((const float4*)partO)[o];
            ox += O.x; oy += O.y; oz += O.z; ow += O.w;
            l += partL[o];
        }
        float rl = 1.f / l;
        t[h*4+0] = ox * rl; t[h*4+1] = oy * rl;
        t[h*4+2] = oz * rl; t[h*4+3] = ow * rl;
    }
    #pragma unroll
    for (int j = 0; j < 8; j++) xch[grp][sl][j] = t[grp * 8 + j];
    __syncthreads();
    #pragma unroll
    for (int j = 0; j < 8; j++) t[(1 - grp) * 8 + j] = xch[1 - grp][sl][j];
    float mu = 0.f;
    #pragma unroll
    for (int e = 0; e < 16; e++) mu += t[e];
    mu *= (1.f / 16.f);
    float var = 0.f;
    #pragma unroll
    for (int e = 0; e < 16; e++) { float d = t[e] - mu; var += d * d; }
    var *= (1.f / 16.f);
    float r = rsqrtf(var + 1e-5f);
    const float4* rp = (const float4*)(res + ((size_t)b * SS + s) * 16);
    #pragma unroll
    for (int i = 0; i < 4; i++) {
        float4 a = rp[i];
        t[4*i+0] = (t[4*i+0]-mu)*r*lnag[4*i+0] + lnab[4*i+0] + a.x;
        t[4*i+1] = (t[4*i+1]-mu)*r*lnag[4*i+1] + lnab[4*i+1] + a.y;
        t[4*i+2] = (t[4*i+2]-mu)*r*lnag[4*i+2] + lnab[4*i+2] + a.z;
        t[4*i+3] = (t[4*i+3]-mu)*r*lnag[4*i+3] + lnab[4*i+3] + a.w;
    }
    float mu2 = 0.f;
    #pragma unroll
    for (int e = 0; e < 16; e++) mu2 += t[e];
    mu2 *= (1.f / 16.f);
    float var2 = 0.f;
    #pragma unroll
    for (int e = 0; e < 16; e++) { float d = t[e] - mu2; var2 += d * d; }
    var2 *= (1.f / 16.f);
    float r2 = rsqrtf(var2 + 1e-5f);
    float pef[16]; pe_vals(s, pef);
    #pragma unroll
    for (int e = 0; e < 16; e++)
        t[e] = (t[e]-mu2)*r2*lng[e] + lnb[e] + pef[e];
    if (!grp) { proj16(t, wq, q, b, s); proj16(t, wk, k, b, s); }
    else      { proj16(t, wv, v, b, s); }
}

// Layer-2 epilogue + pool partials over a 256-s chunk (grid 4 x B -> 128 blocks)
__global__ __launch_bounds__(256) void postpool4(const float* __restrict__ partO,
        const float* __restrict__ partL, int nsplit,
        const float* __restrict__ lnag, const float* __restrict__ lnab,
        const float* __restrict__ lng, const float* __restrict__ lnb,
        float* __restrict__ poolp) {
    __shared__ float red[4][17];
    int tid = threadIdx.x;
    int s = blockIdx.x * 256 + tid, b = blockIdx.y;
    float t[16];
    #pragma unroll
    for (int h = 0; h < HH; h++) {
        int bh = b * HH + h;
        float ox = 0.f, oy = 0.f, oz = 0.f, owv = 0.f, l = 0.f;
        for (int c = 0; c < nsplit; c++) {
            size_t o = (size_t)(c * (BB * HH) + bh) * SS + s;
            float4 O = ((const float4*)partO)[o];
            ox += O.x; oy += O.y; oz += O.z; owv += O.w;
            l += partL[o];
        }
        float rl = 1.f / l;
        t[h*4+0] = ox * rl; t[h*4+1] = oy * rl;
        t[h*4+2] = oz * rl; t[h*4+3] = owv * rl;
    }
    float mu = 0.f;
    #pragma unroll
    for (int e = 0; e < 16; e++) mu += t[e];
    mu *= (1.f / 16.f);
    float var = 0.f;
    #pragma unroll
    for (int e = 0; e < 16; e++) { float d = t[e] - mu; var += d * d; }
    var *= (1.f / 16.f);
    float r = rsqrtf(var + 1e-5f);
    #pragma unroll
    for (int e = 0; e < 16; e++) t[e] = (t[e]-mu)*r*lnag[e] + lnab[e];
    float mu2 = 0.f;
    #pragma unroll
    for (int e = 0; e < 16; e++) mu2 += t[e];
    mu2 *= (1.f / 16.f);
    float var2 = 0.f;
    #pragma unroll
    for (int e = 0; e < 16; e++) { float d = t[e] - mu2; var2 += d * d; }
    var2 *= (1.f / 16.f);
    float r2 = rsqrtf(var2 + 1e-5f);
    #pragma unroll
    for (int e = 0; e < 16; e++) t[e] = (t[e]-mu2)*r2*lng[e] + lnb[e];
    // per-wave shuffle reduction over 64 s-positions
    #pragma unroll
    for (int e = 0; e < 16; e++) {
        float vsum = t[e];
        vsum += __shfl_down(vsum, 32);
        vsum += __shfl_down(vsum, 16);
        vsum += __shfl_down(vsum, 8);
        vsum += __shfl_down(vsum, 4);
        vsum += __shfl_down(vsum, 2);
        vsum += __shfl_down(vsum, 1);
        t[e] = vsum;
    }
    if ((tid & 63) == 0) {
        int wv = tid >> 6;
        #pragma unroll
        for (int e = 0; e < 16; e++) red[wv][e] = t[e];
    }
    __syncthreads();
    if (tid < 16)
        poolp[(b * 4 + blockIdx.x) * 16 + tid] =
            red[0][tid] + red[1][tid] + red[2][tid] + red[3][tid];
}

// Final: reduce 4 chunk-partials per b, mean over S, linear 16->10
__global__ __launch_bounds__(512) void final_kernel(const float* __restrict__ poolp,
        const float* __restrict__ ow, const float* __restrict__ ob,
        float* __restrict__ out) {
    int t = threadIdx.x;
    if (t < BB * NCC) {
        int b = t / NCC, c = t - b * NCC;
        float a = ob[c];
        #pragma unroll
        for (int e = 0; e < 16; e++) {
            float sum = poolp[(b*4+0)*16+e] + poolp[(b*4+1)*16+e]
                      + poolp[(b*4+2)*16+e] + poolp[(b*4+3)*16+e];
            a += (sum * (1.f / 1024.f)) * ow[c * 16 + e];
        }
        out[b * NCC + c] = a;
    }
}

extern "C" void kernel_launch(void* const* d_in, const int* in_sizes, int n_in,
                              void* d_out, int out_size, void* d_ws, size_t ws_size,
                              hipStream_t stream) {
    const float* x       = (const float*)d_in[0];
    const float* patch_w = (const float*)d_in[1];
    const float* patch_b = (const float*)d_in[2];
    const float* bn1_g   = (const float*)d_in[3];
    const float* bn1_b   = (const float*)d_in[4];
    const float* emb_w   = (const float*)d_in[5];
    const float* emb_b   = (const float*)d_in[6];
    const float* bn2_g   = (const float*)d_in[7];
    const float* bn2_b   = (const float*)d_in[8];
    const float* dw_w    = (const float*)d_in[9];
    const float* pw_w    = (const float*)d_in[10];
    const float* bn3_g   = (const float*)d_in[11];
    const float* bn3_b   = (const float*)d_in[12];
    const float* q1_w    = (const float*)d_in[13];
    const float* k1_w    = (const float*)d_in[14];
    const float* v1_w    = (const float*)d_in[15];
    const float* lna1_g  = (const float*)d_in[16];
    const float* lna1_b  = (const float*)d_in[17];
    const float* ln1_g   = (const float*)d_in[18];
    const float* ln1_b   = (const float*)d_in[19];
    const float* q2_w    = (const float*)d_in[20];
    const float* k2_w    = (const float*)d_in[21];
    const float* v2_w    = (const float*)d_in[22];
    const float* lna2_g  = (const float*)d_in[23];
    const float* lna2_b  = (const float*)d_in[24];
    const float* ln2_g   = (const float*)d_in[25];
    const float* ln2_b   = (const float*)d_in[26];
    const float* out_w   = (const float*)d_in[27];
    const float* out_b   = (const float*)d_in[28];

    float* ws    = (float*)d_ws;
    float* xsrc  = ws + OFF_XSRC;
    float* q     = ws + OFF_Q;
    float* k     = ws + OFF_K;
    float* v     = ws + OFF_V;
    float* h2    = ws + OFF_H2;
    float* out   = (float*)d_out;

    // attn t-split: 4-way (TC=256) if workspace allows, else 2-way (TC=512)
    int tsplit; float *partO, *partL;
    size_t need4 = (size_t)(OFF_PART + 4 * 131072 * 5 + 2048) * 4;
    if (ws_size >= need4) {
        tsplit = 4;
        partO = ws + OFF_PART;
        partL = ws + OFF_PART + 4 * 131072 * 4;
    } else {
        tsplit = 2;
        partO = ws + OFF_PART;
        partL = ws + OFF_PART + 2 * 131072 * 4;
    }
    float* poolp = ws + OFF_PART + tsplit * 131072 * 5;

    conv12<<<dim3(4, 4, BB), 256, 0, stream>>>(x, patch_w, patch_b, bn1_g, bn1_b,
        emb_w, emb_b, bn2_g, bn2_b, h2);
    dwpwqkv<<<dim3(8, BB), 256, 0, stream>>>(h2, dw_w, pw_w, bn3_g, bn3_b,
        q1_w, k1_w, v1_w, xsrc, q, k, v);

    dim3 agrid(BB * HH, 16, tsplit);
    if (tsplit == 4) attn_mfma<256><<<agrid, 256, 0, stream>>>(q, k, v, partO, partL);
    else             attn_mfma<512><<<agrid, 256, 0, stream>>>(q, k, v, partO, partL);

    post_qkv2<<<dim3(256), 256, 0, stream>>>(partO, partL, tsplit, xsrc,
        lna1_g, lna1_b, ln1_g, ln1_b, q2_w, k2_w, v2_w, q, k, v);

    if (tsplit == 4) attn_mfma<256><<<agrid, 256, 0, stream>>>(q, k, v, partO, partL);
    else             attn_mfma<512><<<agrid, 256, 0, stream>>>(q, k, v, partO, partL);

    postpool4<<<dim3(4, BB), 256, 0, stream>>>(partO, partL, tsplit,
        lna2_g, lna2_b, ln2_g, ln2_b, poolp);
    final_kernel<<<1, 512, 0, stream>>>(poolp, out_w, out_b, out);
}